// Round 10
// baseline (240.563 us; speedup 1.0000x reference)
//
#include <hip/hip_runtime.h>
#include <math.h>

// DenseGATv2Layer: N=4096, IN=128, HEADS=4, OUT_DIM=64.
// R9: R8 post-mortem — all our kernels < 40us (invisible under harness fills);
// remaining time is dispatch count + harness floor. 4 dispatches -> 2:
//  (1) prep_k: pack_mask (blocks 0..2047) + compute_h (2048..2559) fused,
//      keeping R8 internals (LDS-staged x, atomic-free hsum). Also zeroes
//      cnt[64] (visible to aggr via kernel-boundary coherence).
//  (2) gat_aggr: unnormalized MFMA aggregation (R8) + fence/last-block-done
//      reduction: after writing its jq slice each block does release
//      __threadfence() + atomicAdd(cnt[itile]); the 8th block acquire-fences
//      (cross-XCD cache invalidate, G16) and reduces+normalizes the itile
//      straight into out. No spin -> no co-residency assumption.

#define N 4096
#define IN_DIM 128
#define HEADS 4
#define OUT_DIM 64
#define HD 256
#define LOG2E 1.4426950408889634f
#define PSHIFT 8.0f

typedef _Float16 f16x8 __attribute__((ext_vector_type(8)));
typedef __fp16 fp16x2 __attribute__((ext_vector_type(2)));
typedef float f32x4 __attribute__((ext_vector_type(4)));

union F16x8u { fp16x2 h2[4]; f16x8 v; };

// ws layout (bytes)
#define WS_HB_OFF    0u          // _Float16 hb[2048][512]      (2 MB) frag-linear
#define WS_SSRC_OFF  2097152u    // float s_src[N][4]   (scaled by log2e)
#define WS_SDT_OFF   2162688u    // float s_dst_t[4][N] (scaled)
#define WS_BITT_OFF  2228224u    // uint bits_t[64][128][64]    (2 MB)
#define WS_HSUMP_OFF 4325376u    // float hsum_part[512][256]   (512 KB)
#define WS_CNT_OFF   4849664u    // uint cnt[64]                (4 KB slot)
#define WS_PL_OFF    4853760u    // float partial_l[js][N][4]   (512 KB for js=8)
#define WS_PART_OFF  5378048u    // float acc[js][N][256]       (4 MB/slice)
#define WS_NEED8     (5378048u + 8u * 4194304u)
#define WS_NEED2     (5378048u + 2u * 4194304u)

__device__ __forceinline__ float lrelu(float v) { return fmaxf(v, 0.2f * v); }

__device__ __forceinline__ unsigned pack_bytes(unsigned v) {
  return (v & 1u) | ((v >> 7) & 2u) | ((v >> 14) & 4u) | ((v >> 21) & 8u);
}

// ---------------- K1: fused mask-pack + h-compute + cnt zero ----------------
__global__ __launch_bounds__(256) void prep_k(const void* __restrict__ mraw,
                                              unsigned* __restrict__ bits_t,
                                              const float* __restrict__ x,
                                              const float* __restrict__ W,
                                              const float* __restrict__ a_src,
                                              const float* __restrict__ a_dst,
                                              _Float16* __restrict__ hb,
                                              float* __restrict__ s_src,
                                              float* __restrict__ s_dst_t,
                                              float* __restrict__ hsum_part,
                                              unsigned* __restrict__ cnt) {
  if (blockIdx.x < 2048) {
    if (blockIdx.x < 64 && threadIdx.x == 0) cnt[blockIdx.x] = 0u;

    // ---- mask pack: detect format from first 4KB (L2 broadcast) ----
    __shared__ int s_flag;
    if (threadIdx.x == 0) s_flag = 0;
    __syncthreads();
    const unsigned* mw = (const unsigned*)mraw;
    int bad = 0, g = 0;
    for (int i = threadIdx.x; i < 1024; i += 256) {
      unsigned v = mw[i];
      if (v & 0xFEFEFEFEu) bad = 1;
      if (v > 1u) g = 1;
    }
    if (bad || g) atomicOr(&s_flag, (bad ? 1 : 0) | (g ? 2 : 0));
    __syncthreads();
    const bool byte_fmt = ((s_flag & 1) == 0) && ((s_flag & 2) != 0);

    int w = blockIdx.x * 256 + threadIdx.x;  // word idx, N*N/32 total
    unsigned ob = 0u;
    if (byte_fmt) {
      const uint4* p = (const uint4*)((const unsigned char*)mraw + (size_t)w * 32u);
      uint4 a = p[0], b = p[1];
      ob  =  pack_bytes(a.x)        | (pack_bytes(a.y) << 4)  | (pack_bytes(a.z) << 8)  | (pack_bytes(a.w) << 12);
      ob |= (pack_bytes(b.x) << 16) | (pack_bytes(b.y) << 20) | (pack_bytes(b.z) << 24) | (pack_bytes(b.w) << 28);
    } else {
      const uint4* p = (const uint4*)((const unsigned*)mraw + (size_t)w * 32u);
#pragma unroll
      for (int k = 0; k < 8; ++k) {
        uint4 v = p[k];
        ob |= (v.x ? 1u : 0u) << (4 * k);
        ob |= (v.y ? 1u : 0u) << (4 * k + 1);
        ob |= (v.z ? 1u : 0u) << (4 * k + 2);
        ob |= (v.w ? 1u : 0u) << (4 * k + 3);
      }
    }
    const int row = w >> 7, jc = w & 127;
    bits_t[((size_t)(row >> 6) * 128 + jc) * 64 + (row & 63)] = ob;
  } else {
    // ---- h = x@W (8 rows), LDS-staged x, frag-linear hb, s vectors, hsum ----
    __shared__ float xs[8][IN_DIM];  // 4 KB
    const int blk = blockIdx.x - 2048;
    const int i0 = blk * 8;
    const int c = threadIdx.x;

    ((float4*)&xs[0][0])[c] = ((const float4*)(x + (size_t)i0 * IN_DIM))[c];
    __syncthreads();

    float acc[8];
#pragma unroll
    for (int r = 0; r < 8; ++r) acc[r] = 0.f;

    for (int kk = 0; kk < IN_DIM / 4; ++kk) {
      const int k = kk * 4;
      float w0 = W[(size_t)(k + 0) * HD + c];
      float w1 = W[(size_t)(k + 1) * HD + c];
      float w2 = W[(size_t)(k + 2) * HD + c];
      float w3 = W[(size_t)(k + 3) * HD + c];
#pragma unroll
      for (int r = 0; r < 8; ++r) {
        float4 xv = *(const float4*)(&xs[r][k]);  // wave-uniform LDS broadcast
        acc[r] = fmaf(xv.x, w0, fmaf(xv.y, w1, fmaf(xv.z, w2, fmaf(xv.w, w3, acc[r]))));
      }
    }

    // frag-linear store: unit=(head, chunk=i0>>5, nt); elem(lane', t=r)
    {
      const int head = c >> 6, nt = (c >> 4) & 3, m15 = c & 15;
      const int unit = (head * 128 + (i0 >> 5)) * 4 + nt;
      const int lanep = ((i0 & 31) >> 3) * 16 + m15;
      f16x8 v;
#pragma unroll
      for (int r = 0; r < 8; ++r) v[r] = (_Float16)acc[r];
      *(f16x8*)(hb + (size_t)unit * 512 + lanep * 8) = v;
    }

    // per-block column sums (plain store) for empty-row fallback
    {
      float loc = 0.f;
#pragma unroll
      for (int r = 0; r < 8; ++r) loc += acc[r];
      hsum_part[(size_t)blk * HD + c] = loc;
    }

    const int hw = c >> 6, lane = c & 63;
    const float as = a_src[lane], ad = a_dst[lane];
#pragma unroll
    for (int r = 0; r < 8; ++r) {
      float vs = acc[r] * as, vd = acc[r] * ad;
#pragma unroll
      for (int off = 1; off < 64; off <<= 1) {
        vs += __shfl_xor(vs, off);
        vd += __shfl_xor(vd, off);
      }
      if (lane == 0) {
        s_src[(size_t)(i0 + r) * HEADS + hw] = vs * LOG2E;
        s_dst_t[(size_t)hw * N + (i0 + r)] = vd * LOG2E;
      }
    }
  }
}

// ---------------- K2: MFMA aggregation + in-kernel reduction ----------------
// grid = 64 itiles x jsplit; 512 thr (8 waves). wave = (head, mg); rows
// rA = i0+mg*32+m15, rB = rA+16. p~ = 2^((mask? lrelu(si+sj): -1e38) - 8).
// Tail: release fence + cnt[it]++; 8th block acquire-fences and reduces.
__global__ __launch_bounds__(512, 4) void gat_aggr(const _Float16* __restrict__ hb,
                                                   const float* __restrict__ s_src,
                                                   const float* __restrict__ s_dst_t,
                                                   const unsigned* __restrict__ bits_t,
                                                   float* __restrict__ accp,
                                                   float* __restrict__ lp,
                                                   const float* __restrict__ hsum_part,
                                                   unsigned* __restrict__ cnt,
                                                   float* __restrict__ out,
                                                   int jshift) {
  __shared__ unsigned s_old;
  const int jsplit = 1 << jshift;
  const int jrange = N >> jshift;
  const int chunks = jrange >> 5;
  const int tid = threadIdx.x;
  const int wave = tid >> 6;
  const int lane = tid & 63;
  const int head = wave & 3;
  const int mg = wave >> 2;
  const int m15 = lane & 15;
  const int quad = lane >> 4;
  const int jq = blockIdx.x & (jsplit - 1);
  const int it = blockIdx.x >> jshift;
  const int i0 = it * 64;
  const int rA = i0 + mg * 32 + m15;
  const int rB = rA + 16;

  const float siA = s_src[(size_t)rA * HEADS + head];
  const float siB = s_src[(size_t)rB * HEADS + head];

  const unsigned* mt = bits_t + ((size_t)it * 128 + jq * chunks) * 64 + mg * 32 + m15;
  const float* sjb = s_dst_t + (size_t)head * N + jq * jrange + quad * 8;
  const _Float16* hbp = hb + ((size_t)(head * 128 + jq * chunks) * 4) * 512 + lane * 8;

  f32x4 accA0 = {0.f, 0.f, 0.f, 0.f}, accA1 = accA0, accA2 = accA0, accA3 = accA0;
  f32x4 accB0 = accA0, accB1 = accA0, accB2 = accA0, accB3 = accA0;
  float lA = 0.f, lB = 0.f;

  const int shq = quad * 8;

  for (int c = 0; c < chunks; ++c) {
    const unsigned mwA = mt[c * 64];
    const unsigned mwB = mt[c * 64 + 16];
    const float4 sa = *(const float4*)(sjb + c * 32);
    const float4 sb = *(const float4*)(sjb + c * 32 + 4);

    const f16x8 b0 = *(const f16x8*)(hbp + (size_t)(c * 4 + 0) * 512);
    const f16x8 b1 = *(const f16x8*)(hbp + (size_t)(c * 4 + 1) * 512);
    const f16x8 b2 = *(const f16x8*)(hbp + (size_t)(c * 4 + 2) * 512);
    const f16x8 b3 = *(const f16x8*)(hbp + (size_t)(c * 4 + 3) * 512);

    const unsigned wA = mwA >> shq;
    const unsigned wB = mwB >> shq;
    const float sjs[8] = {sa.x, sa.y, sa.z, sa.w, sb.x, sb.y, sb.z, sb.w};

    F16x8u uA, uB;
#pragma unroll
    for (int t2 = 0; t2 < 4; ++t2) {
      float pA[2], pB[2];
#pragma unroll
      for (int q = 0; q < 2; ++q) {
        const int t = t2 * 2 + q;
        const float sj = sjs[t];
        float vA = lrelu(siA + sj);
        float vB = lrelu(siB + sj);
        float xA = (((wA >> t) & 1u) ? vA : -1.0e38f) - PSHIFT;
        float xB = (((wB >> t) & 1u) ? vB : -1.0e38f) - PSHIFT;
        pA[q] = __builtin_amdgcn_exp2f(xA);
        pB[q] = __builtin_amdgcn_exp2f(xB);
        lA += pA[q];
        lB += pB[q];
      }
      uA.h2[t2] = __builtin_amdgcn_cvt_pkrtz(pA[0], pA[1]);
      uB.h2[t2] = __builtin_amdgcn_cvt_pkrtz(pB[0], pB[1]);
    }

    accA0 = __builtin_amdgcn_mfma_f32_16x16x32_f16(uA.v, b0, accA0, 0, 0, 0);
    accA1 = __builtin_amdgcn_mfma_f32_16x16x32_f16(uA.v, b1, accA1, 0, 0, 0);
    accA2 = __builtin_amdgcn_mfma_f32_16x16x32_f16(uA.v, b2, accA2, 0, 0, 0);
    accA3 = __builtin_amdgcn_mfma_f32_16x16x32_f16(uA.v, b3, accA3, 0, 0, 0);
    accB0 = __builtin_amdgcn_mfma_f32_16x16x32_f16(uB.v, b0, accB0, 0, 0, 0);
    accB1 = __builtin_amdgcn_mfma_f32_16x16x32_f16(uB.v, b1, accB1, 0, 0, 0);
    accB2 = __builtin_amdgcn_mfma_f32_16x16x32_f16(uB.v, b2, accB2, 0, 0, 0);
    accB3 = __builtin_amdgcn_mfma_f32_16x16x32_f16(uB.v, b3, accB3, 0, 0, 0);
  }

  // l partials across the 4 quads
  lA += __shfl_xor(lA, 16); lA += __shfl_xor(lA, 32);
  lB += __shfl_xor(lB, 16); lB += __shfl_xor(lB, 32);
  if (quad == 0) {
    lp[((size_t)jq * N + rA) * HEADS + head] = lA;
    lp[((size_t)jq * N + rB) * HEADS + head] = lB;
  }

  // partial slice store (disjoint per jq)
  const int colb = head * 64 + m15;
  float* oA = accp + (size_t)jq * (N * HD) + (size_t)(i0 + mg * 32 + quad * 4) * HD + colb;
  float* oB = oA + (size_t)16 * HD;
#pragma unroll
  for (int reg = 0; reg < 4; ++reg) {
    oA[(size_t)reg * HD + 0]  = accA0[reg];
    oA[(size_t)reg * HD + 16] = accA1[reg];
    oA[(size_t)reg * HD + 32] = accA2[reg];
    oA[(size_t)reg * HD + 48] = accA3[reg];
    oB[(size_t)reg * HD + 0]  = accB0[reg];
    oB[(size_t)reg * HD + 16] = accB1[reg];
    oB[(size_t)reg * HD + 32] = accB2[reg];
    oB[(size_t)reg * HD + 48] = accB3[reg];
  }

  // ---- last-block-done reduction for this itile ----
  __syncthreads();
  if (tid == 0) {
    __threadfence();                       // release: L2 writeback
    s_old = atomicAdd(&cnt[it], 1u);
  }
  __syncthreads();
  if (s_old == (unsigned)(jsplit - 1)) {
    __threadfence();                       // acquire: invalidate local caches
    const size_t S = (size_t)N * HD;
    for (int e = tid; e < 64 * 64; e += 512) {   // 64 rows x 64 float4s
      const int r = e >> 6;
      const int c4 = e & 63;
      const int row = i0 + r;
      const int hd = c4 >> 4;
      float4 o = {0.f, 0.f, 0.f, 0.f};
      float lt = 0.f;
      for (int k = 0; k < jsplit; ++k) {
        float4 a = *((const float4*)(accp + (size_t)k * S) + (size_t)row * 64 + c4);
        o.x += a.x; o.y += a.y; o.z += a.z; o.w += a.w;
        lt += lp[((size_t)k * N + row) * HEADS + hd];
      }
      if (lt == 0.f) {
        // empty row -> exact uniform 1/N
        float4 hs = {0.f, 0.f, 0.f, 0.f};
        for (int b = 0; b < 512; ++b) {
          float4 t = ((const float4*)hsum_part)[(size_t)b * 64 + c4];
          hs.x += t.x; hs.y += t.y; hs.z += t.z; hs.w += t.w;
        }
        const float cst = 1.0f / (float)N;
        o.x = hs.x * cst; o.y = hs.y * cst; o.z = hs.z * cst; o.w = hs.w * cst;
      } else {
        const float inv = 1.0f / lt;
        o.x *= inv; o.y *= inv; o.z *= inv; o.w *= inv;
      }
      ((float4*)out)[(size_t)row * 64 + c4] = o;
    }
  }
}

extern "C" void kernel_launch(void* const* d_in, const int* in_sizes, int n_in,
                              void* d_out, int out_size, void* d_ws, size_t ws_size,
                              hipStream_t stream) {
  (void)in_sizes; (void)n_in; (void)out_size;
  const float* x = (const float*)d_in[0];
  const void* mask = d_in[1];
  const float* W = (const float*)d_in[2];
  const float* a_src = (const float*)d_in[3];
  const float* a_dst = (const float*)d_in[4];
  float* out = (float*)d_out;

  char* ws = (char*)d_ws;
  _Float16* hb = (_Float16*)(ws + WS_HB_OFF);
  float* s_src = (float*)(ws + WS_SSRC_OFF);
  float* s_dst_t = (float*)(ws + WS_SDT_OFF);
  unsigned* bits_t = (unsigned*)(ws + WS_BITT_OFF);
  float* hsum_part = (float*)(ws + WS_HSUMP_OFF);
  unsigned* cnt = (unsigned*)(ws + WS_CNT_OFF);
  float* lp = (float*)(ws + WS_PL_OFF);
  float* accp = (float*)(ws + WS_PART_OFF);

  const int jshift = (ws_size >= (size_t)WS_NEED8) ? 3 : 1;  // 8 (XCD-aligned) or 2
  const int jsplit = 1 << jshift;

  prep_k<<<2048 + N / 8, 256, 0, stream>>>(mask, bits_t, x, W, a_src, a_dst,
                                           hb, s_src, s_dst_t, hsum_part, cnt);
  gat_aggr<<<(N / 64) * jsplit, 512, 0, stream>>>(hb, s_src, s_dst_t, bits_t,
                                                  accp, lp, hsum_part, cnt, out, jshift);
}

// Round 11
// 152.129 us; speedup vs baseline: 1.5813x; 1.5813x over previous
//
#include <hip/hip_runtime.h>
#include <math.h>

// DenseGATv2Layer: N=4096, IN=128, HEADS=4, OUT_DIM=64.
// R10: R9 post-mortem — fence/last-block reduction REGRESSED 8x (170us aggr):
// device-scope __threadfence per block = L2 writeback/invalidate serialized on
// TCC; kernel-boundary coherence is cheaper than in-kernel cross-XCD fences.
// Revert to R8's proven structure, keep R9's harmless prep fusion:
//   D1 prep_k    : mask pack (blocks 0..2047, format-detect) + h=x@W
//                  (2048..2559, LDS-staged x, frag-linear fp16 hb, scaled s,
//                  atomic-free hsum_part).
//   D2 gat_aggr  : unnormalized MFMA aggregation (R8), partial slices + lp.
//   D3 reduce_part: combine jsplit slices, normalize, empty-row fallback.

#define N 4096
#define IN_DIM 128
#define HEADS 4
#define OUT_DIM 64
#define HD 256
#define LOG2E 1.4426950408889634f
#define PSHIFT 8.0f

typedef _Float16 f16x8 __attribute__((ext_vector_type(8)));
typedef __fp16 fp16x2 __attribute__((ext_vector_type(2)));
typedef float f32x4 __attribute__((ext_vector_type(4)));

union F16x8u { fp16x2 h2[4]; f16x8 v; };

// ws layout (bytes)
#define WS_HB_OFF    0u          // _Float16 hb[2048][512]      (2 MB) frag-linear
#define WS_SSRC_OFF  2097152u    // float s_src[N][4]   (scaled by log2e)
#define WS_SDT_OFF   2162688u    // float s_dst_t[4][N] (scaled)
#define WS_BITT_OFF  2228224u    // uint bits_t[64][128][64]    (2 MB)
#define WS_HSUMP_OFF 4325376u    // float hsum_part[512][256]   (512 KB)
#define WS_PL_OFF    4849664u    // float partial_l[js][N][4]   (64 KB/slice)
#define WS_PART_OFF  5373952u    // float acc[js][N][256]       (4 MB/slice)
#define WS_NEED8     (5373952u + 8u * 4194304u)

__device__ __forceinline__ float lrelu(float v) { return fmaxf(v, 0.2f * v); }

__device__ __forceinline__ unsigned pack_bytes(unsigned v) {
  return (v & 1u) | ((v >> 7) & 2u) | ((v >> 14) & 4u) | ((v >> 21) & 8u);
}

// ---------------- D1: fused mask-pack + h-compute ----------------
__global__ __launch_bounds__(256) void prep_k(const void* __restrict__ mraw,
                                              unsigned* __restrict__ bits_t,
                                              const float* __restrict__ x,
                                              const float* __restrict__ W,
                                              const float* __restrict__ a_src,
                                              const float* __restrict__ a_dst,
                                              _Float16* __restrict__ hb,
                                              float* __restrict__ s_src,
                                              float* __restrict__ s_dst_t,
                                              float* __restrict__ hsum_part) {
  if (blockIdx.x < 2048) {
    // ---- mask pack: detect format from first 4KB (L2 broadcast) ----
    __shared__ int s_flag;
    if (threadIdx.x == 0) s_flag = 0;
    __syncthreads();
    const unsigned* mw = (const unsigned*)mraw;
    int bad = 0, g = 0;
    for (int i = threadIdx.x; i < 1024; i += 256) {
      unsigned v = mw[i];
      if (v & 0xFEFEFEFEu) bad = 1;
      if (v > 1u) g = 1;
    }
    if (bad || g) atomicOr(&s_flag, (bad ? 1 : 0) | (g ? 2 : 0));
    __syncthreads();
    const bool byte_fmt = ((s_flag & 1) == 0) && ((s_flag & 2) != 0);

    int w = blockIdx.x * 256 + threadIdx.x;  // word idx, N*N/32 total
    unsigned ob = 0u;
    if (byte_fmt) {
      const uint4* p = (const uint4*)((const unsigned char*)mraw + (size_t)w * 32u);
      uint4 a = p[0], b = p[1];
      ob  =  pack_bytes(a.x)        | (pack_bytes(a.y) << 4)  | (pack_bytes(a.z) << 8)  | (pack_bytes(a.w) << 12);
      ob |= (pack_bytes(b.x) << 16) | (pack_bytes(b.y) << 20) | (pack_bytes(b.z) << 24) | (pack_bytes(b.w) << 28);
    } else {
      const uint4* p = (const uint4*)((const unsigned*)mraw + (size_t)w * 32u);
#pragma unroll
      for (int k = 0; k < 8; ++k) {
        uint4 v = p[k];
        ob |= (v.x ? 1u : 0u) << (4 * k);
        ob |= (v.y ? 1u : 0u) << (4 * k + 1);
        ob |= (v.z ? 1u : 0u) << (4 * k + 2);
        ob |= (v.w ? 1u : 0u) << (4 * k + 3);
      }
    }
    const int row = w >> 7, jc = w & 127;
    bits_t[((size_t)(row >> 6) * 128 + jc) * 64 + (row & 63)] = ob;
  } else {
    // ---- h = x@W (8 rows), LDS-staged x, frag-linear hb, s vectors, hsum ----
    __shared__ float xs[8][IN_DIM];  // 4 KB
    const int blk = blockIdx.x - 2048;
    const int i0 = blk * 8;
    const int c = threadIdx.x;

    ((float4*)&xs[0][0])[c] = ((const float4*)(x + (size_t)i0 * IN_DIM))[c];
    __syncthreads();

    float acc[8];
#pragma unroll
    for (int r = 0; r < 8; ++r) acc[r] = 0.f;

    for (int kk = 0; kk < IN_DIM / 4; ++kk) {
      const int k = kk * 4;
      float w0 = W[(size_t)(k + 0) * HD + c];
      float w1 = W[(size_t)(k + 1) * HD + c];
      float w2 = W[(size_t)(k + 2) * HD + c];
      float w3 = W[(size_t)(k + 3) * HD + c];
#pragma unroll
      for (int r = 0; r < 8; ++r) {
        float4 xv = *(const float4*)(&xs[r][k]);  // wave-uniform LDS broadcast
        acc[r] = fmaf(xv.x, w0, fmaf(xv.y, w1, fmaf(xv.z, w2, fmaf(xv.w, w3, acc[r]))));
      }
    }

    // frag-linear store: unit=(head, chunk=i0>>5, nt); elem(lane', t=r)
    {
      const int head = c >> 6, nt = (c >> 4) & 3, m15 = c & 15;
      const int unit = (head * 128 + (i0 >> 5)) * 4 + nt;
      const int lanep = ((i0 & 31) >> 3) * 16 + m15;
      f16x8 v;
#pragma unroll
      for (int r = 0; r < 8; ++r) v[r] = (_Float16)acc[r];
      *(f16x8*)(hb + (size_t)unit * 512 + lanep * 8) = v;
    }

    // per-block column sums (plain store, no atomics) for empty-row fallback
    {
      float loc = 0.f;
#pragma unroll
      for (int r = 0; r < 8; ++r) loc += acc[r];
      hsum_part[(size_t)blk * HD + c] = loc;
    }

    const int hw = c >> 6, lane = c & 63;
    const float as = a_src[lane], ad = a_dst[lane];
#pragma unroll
    for (int r = 0; r < 8; ++r) {
      float vs = acc[r] * as, vd = acc[r] * ad;
#pragma unroll
      for (int off = 1; off < 64; off <<= 1) {
        vs += __shfl_xor(vs, off);
        vd += __shfl_xor(vd, off);
      }
      if (lane == 0) {
        s_src[(size_t)(i0 + r) * HEADS + hw] = vs * LOG2E;
        s_dst_t[(size_t)hw * N + (i0 + r)] = vd * LOG2E;
      }
    }
  }
}

// ---------------- D2: MFMA aggregation, unnormalized, l in-loop (R8) ----------------
__global__ __launch_bounds__(512, 4) void gat_aggr(const _Float16* __restrict__ hb,
                                                   const float* __restrict__ s_src,
                                                   const float* __restrict__ s_dst_t,
                                                   const unsigned* __restrict__ bits_t,
                                                   float* __restrict__ accp,
                                                   float* __restrict__ lp,
                                                   int jshift) {
  const int jsplit = 1 << jshift;
  const int jrange = N >> jshift;
  const int chunks = jrange >> 5;
  const int tid = threadIdx.x;
  const int wave = tid >> 6;
  const int lane = tid & 63;
  const int head = wave & 3;
  const int mg = wave >> 2;
  const int m15 = lane & 15;
  const int quad = lane >> 4;
  const int jq = blockIdx.x & (jsplit - 1);
  const int it = blockIdx.x >> jshift;
  const int i0 = it * 64;
  const int rA = i0 + mg * 32 + m15;
  const int rB = rA + 16;

  const float siA = s_src[(size_t)rA * HEADS + head];
  const float siB = s_src[(size_t)rB * HEADS + head];

  const unsigned* mt = bits_t + ((size_t)it * 128 + jq * chunks) * 64 + mg * 32 + m15;
  const float* sjb = s_dst_t + (size_t)head * N + jq * jrange + quad * 8;
  const _Float16* hbp = hb + ((size_t)(head * 128 + jq * chunks) * 4) * 512 + lane * 8;

  f32x4 accA0 = {0.f, 0.f, 0.f, 0.f}, accA1 = accA0, accA2 = accA0, accA3 = accA0;
  f32x4 accB0 = accA0, accB1 = accA0, accB2 = accA0, accB3 = accA0;
  float lA = 0.f, lB = 0.f;

  const int shq = quad * 8;

  for (int c = 0; c < chunks; ++c) {
    const unsigned mwA = mt[c * 64];
    const unsigned mwB = mt[c * 64 + 16];
    const float4 sa = *(const float4*)(sjb + c * 32);
    const float4 sb = *(const float4*)(sjb + c * 32 + 4);

    const f16x8 b0 = *(const f16x8*)(hbp + (size_t)(c * 4 + 0) * 512);
    const f16x8 b1 = *(const f16x8*)(hbp + (size_t)(c * 4 + 1) * 512);
    const f16x8 b2 = *(const f16x8*)(hbp + (size_t)(c * 4 + 2) * 512);
    const f16x8 b3 = *(const f16x8*)(hbp + (size_t)(c * 4 + 3) * 512);

    const unsigned wA = mwA >> shq;
    const unsigned wB = mwB >> shq;
    const float sjs[8] = {sa.x, sa.y, sa.z, sa.w, sb.x, sb.y, sb.z, sb.w};

    F16x8u uA, uB;
#pragma unroll
    for (int t2 = 0; t2 < 4; ++t2) {
      float pA[2], pB[2];
#pragma unroll
      for (int q = 0; q < 2; ++q) {
        const int t = t2 * 2 + q;
        const float sj = sjs[t];
        float vA = lrelu(siA + sj);
        float vB = lrelu(siB + sj);
        float xA = (((wA >> t) & 1u) ? vA : -1.0e38f) - PSHIFT;
        float xB = (((wB >> t) & 1u) ? vB : -1.0e38f) - PSHIFT;
        pA[q] = __builtin_amdgcn_exp2f(xA);
        pB[q] = __builtin_amdgcn_exp2f(xB);
        lA += pA[q];
        lB += pB[q];
      }
      uA.h2[t2] = __builtin_amdgcn_cvt_pkrtz(pA[0], pA[1]);
      uB.h2[t2] = __builtin_amdgcn_cvt_pkrtz(pB[0], pB[1]);
    }

    accA0 = __builtin_amdgcn_mfma_f32_16x16x32_f16(uA.v, b0, accA0, 0, 0, 0);
    accA1 = __builtin_amdgcn_mfma_f32_16x16x32_f16(uA.v, b1, accA1, 0, 0, 0);
    accA2 = __builtin_amdgcn_mfma_f32_16x16x32_f16(uA.v, b2, accA2, 0, 0, 0);
    accA3 = __builtin_amdgcn_mfma_f32_16x16x32_f16(uA.v, b3, accA3, 0, 0, 0);
    accB0 = __builtin_amdgcn_mfma_f32_16x16x32_f16(uB.v, b0, accB0, 0, 0, 0);
    accB1 = __builtin_amdgcn_mfma_f32_16x16x32_f16(uB.v, b1, accB1, 0, 0, 0);
    accB2 = __builtin_amdgcn_mfma_f32_16x16x32_f16(uB.v, b2, accB2, 0, 0, 0);
    accB3 = __builtin_amdgcn_mfma_f32_16x16x32_f16(uB.v, b3, accB3, 0, 0, 0);
  }

  lA += __shfl_xor(lA, 16); lA += __shfl_xor(lA, 32);
  lB += __shfl_xor(lB, 16); lB += __shfl_xor(lB, 32);
  if (quad == 0) {
    lp[((size_t)jq * N + rA) * HEADS + head] = lA;
    lp[((size_t)jq * N + rB) * HEADS + head] = lB;
  }

  const int colb = head * 64 + m15;
  float* oA = accp + (size_t)jq * (N * HD) + (size_t)(i0 + mg * 32 + quad * 4) * HD + colb;
  float* oB = oA + (size_t)16 * HD;
#pragma unroll
  for (int reg = 0; reg < 4; ++reg) {
    oA[(size_t)reg * HD + 0]  = accA0[reg];
    oA[(size_t)reg * HD + 16] = accA1[reg];
    oA[(size_t)reg * HD + 32] = accA2[reg];
    oA[(size_t)reg * HD + 48] = accA3[reg];
    oB[(size_t)reg * HD + 0]  = accB0[reg];
    oB[(size_t)reg * HD + 16] = accB1[reg];
    oB[(size_t)reg * HD + 32] = accB2[reg];
    oB[(size_t)reg * HD + 48] = accB3[reg];
  }
}

// ---------------- D3: combine slices + normalize (+ rare empty-row fallback) ----
__global__ __launch_bounds__(256) void reduce_part(const float4* __restrict__ accp,
                                                   const float* __restrict__ lp,
                                                   const float* __restrict__ hsum_part,
                                                   float4* __restrict__ out, int jsplit) {
  const size_t idx = (size_t)blockIdx.x * 256 + threadIdx.x;  // [N][64] float4s
  const int row = (int)(idx >> 6);
  const int col4 = (int)(idx & 63);
  const int head = col4 >> 4;
  const size_t S = (size_t)N * HD / 4;

  float4 o = accp[idx];
  float lt = lp[(size_t)row * HEADS + head];
  for (int k = 1; k < jsplit; ++k) {
    float4 a = accp[idx + (size_t)k * S];
    o.x += a.x; o.y += a.y; o.z += a.z; o.w += a.w;
    lt += lp[((size_t)k * N + row) * HEADS + head];
  }
  if (lt == 0.f) {
    // empty row -> exact uniform 1/N: sum h over all j (512 block slices)
    float4 hs = {0.f, 0.f, 0.f, 0.f};
    for (int b = 0; b < 512; ++b) {
      float4 t = ((const float4*)hsum_part)[(size_t)b * 64 + col4];
      hs.x += t.x; hs.y += t.y; hs.z += t.z; hs.w += t.w;
    }
    const float cst = 1.0f / (float)N;
    o.x = hs.x * cst; o.y = hs.y * cst; o.z = hs.z * cst; o.w = hs.w * cst;
  } else {
    const float inv = 1.0f / lt;
    o.x *= inv; o.y *= inv; o.z *= inv; o.w *= inv;
  }
  out[idx] = o;
}

extern "C" void kernel_launch(void* const* d_in, const int* in_sizes, int n_in,
                              void* d_out, int out_size, void* d_ws, size_t ws_size,
                              hipStream_t stream) {
  (void)in_sizes; (void)n_in; (void)out_size;
  const float* x = (const float*)d_in[0];
  const void* mask = d_in[1];
  const float* W = (const float*)d_in[2];
  const float* a_src = (const float*)d_in[3];
  const float* a_dst = (const float*)d_in[4];
  float* out = (float*)d_out;

  char* ws = (char*)d_ws;
  _Float16* hb = (_Float16*)(ws + WS_HB_OFF);
  float* s_src = (float*)(ws + WS_SSRC_OFF);
  float* s_dst_t = (float*)(ws + WS_SDT_OFF);
  unsigned* bits_t = (unsigned*)(ws + WS_BITT_OFF);
  float* hsum_part = (float*)(ws + WS_HSUMP_OFF);
  float* lp = (float*)(ws + WS_PL_OFF);
  float* accp = (float*)(ws + WS_PART_OFF);

  const int jshift = (ws_size >= (size_t)WS_NEED8) ? 3 : 1;  // 8 (XCD-aligned) or 2
  const int jsplit = 1 << jshift;

  prep_k<<<2048 + N / 8, 256, 0, stream>>>(mask, bits_t, x, W, a_src, a_dst,
                                           hb, s_src, s_dst_t, hsum_part);
  gat_aggr<<<(N / 64) * jsplit, 512, 0, stream>>>(hb, s_src, s_dst_t, bits_t,
                                                  accp, lp, jshift);
  reduce_part<<<(N * HD / 4) / 256, 256, 0, stream>>>((const float4*)accp, lp, hsum_part,
                                                      (float4*)out, jsplit);
}